// Round 6
// baseline (4216.677 us; speedup 1.0000x reference)
//
#include <hip/hip_runtime.h>
#include <math.h>

#define Hh  8
#define Dd  512
#define SUB 256          // D/2
#define Nk  1024         // num_subkeys
#define TK  32           // top_k
#define Rr  8            // rows (b,c) per block
#define NT  256
#define W_ELEMS (65536 * 32)

// Phase-1 arithmetic: single accumulator per (row,key), strictly sequential
// FUSED-FMA chain over the contraction dim in natural order (d = 0..255) —
// bit-identical to all previous rounds.
//
// R6 structural changes (no arithmetic change):
//  - sc shrunk to 4 rows (16 KB): scores live in acc[8][4] registers, so
//    selection runs in TWO batches (rows 0-3, then 4-7), one row per wave.
//    LDS 52.8 -> 36 KB  =>  4 blocks/CU (16 waves/CU, was 12).
//  - phase-1 software pipeline: key float4s double-buffered (prefetch idx+1
//    during idx's FMAs); q ds_reads split in two 4-row halves to interleave
//    lgkm waits with FMAs.
//  - selection identical to R5 (DPP value-max + ballot/ctz tie-break, static
//    cndmask elimination; lane l owns keys [16l,16l+16); sc XOR-swizzled).

__device__ __forceinline__ float wave_fmax_bcast(float x) {
    // classic gfx9 DPP max-reduce; result broadcast via readlane(63).
    int v;
    v = __builtin_amdgcn_update_dpp(0xff800000, __float_as_int(x), 0x111, 0xf, 0xf, false);
    x = fmaxf(x, __int_as_float(v));   // row_shr:1
    v = __builtin_amdgcn_update_dpp(0xff800000, __float_as_int(x), 0x112, 0xf, 0xf, false);
    x = fmaxf(x, __int_as_float(v));   // row_shr:2
    v = __builtin_amdgcn_update_dpp(0xff800000, __float_as_int(x), 0x114, 0xf, 0xf, false);
    x = fmaxf(x, __int_as_float(v));   // row_shr:4
    v = __builtin_amdgcn_update_dpp(0xff800000, __float_as_int(x), 0x118, 0xf, 0xf, false);
    x = fmaxf(x, __int_as_float(v));   // row_shr:8  -> lane15 of each row16 = row max
    v = __builtin_amdgcn_update_dpp(0xff800000, __float_as_int(x), 0x142, 0xa, 0xf, false);
    x = fmaxf(x, __int_as_float(v));   // row_bcast:15
    v = __builtin_amdgcn_update_dpp(0xff800000, __float_as_int(x), 0x143, 0xc, 0xf, false);
    x = fmaxf(x, __int_as_float(v));   // row_bcast:31 -> lane 63 = wave max
    return __int_as_float(__builtin_amdgcn_readlane(__float_as_int(x), 63));
}

__global__ __launch_bounds__(NT, 4)
void pk_kernel(const float* __restrict__ query,
               const float* __restrict__ keyl,
               const float* __restrict__ keyr,
               float* __restrict__ out)
{
    __shared__ __attribute__((aligned(16))) float qs[Rr][Dd];      // 16 KB
    __shared__ __attribute__((aligned(16))) float sc[4][Nk];       // 16 KB (swizzled)
    __shared__ __attribute__((aligned(16))) float topv[2][Rr][TK]; // 2 KB
    __shared__ __attribute__((aligned(16))) int   topi[2][Rr][TK]; // 2 KB

    const int bid  = blockIdx.x;
    const int h    = bid >> 10;           // h-major for L2 key locality
    const int tile = bid & 1023;
    const int bc0  = tile * Rr;
    const int t    = threadIdx.x;
    const int lane = t & 63;
    const int wave = t >> 6;

    // ---- stage query tile to LDS, fully coalesced ----
    #pragma unroll
    for (int rw = 0; rw < 2; ++rw) {
        const int r = wave * 2 + rw;
        const float4* src = (const float4*)(query + ((size_t)(bc0 + r) * Hh + h) * Dd);
        float4* dst = (float4*)qs[r];
        dst[lane]      = src[lane];
        dst[lane + 64] = src[lane + 64];
    }
    __syncthreads();

    const int X = ((t >> 4) & 7) << 2;    // store-swizzle for this thread

    for (int side = 0; side < 2; ++side) {
        const float* kbase = (side == 0 ? keyl : keyr) + (size_t)h * Nk * SUB;

        const float4* kr0 = (const float4*)(kbase + (size_t)(0 * 256 + t) * SUB);
        const float4* kr1 = (const float4*)(kbase + (size_t)(1 * 256 + t) * SUB);
        const float4* kr2 = (const float4*)(kbase + (size_t)(2 * 256 + t) * SUB);
        const float4* kr3 = (const float4*)(kbase + (size_t)(3 * 256 + t) * SUB);

        float acc[Rr][4];
        #pragma unroll
        for (int r = 0; r < Rr; ++r)
            #pragma unroll
            for (int g = 0; g < 4; ++g) acc[r][g] = 0.0f;

        // ---- phase 1: k double-buffered, q broadcast from LDS in 2 halves ----
        float4 kc0 = kr0[0], kc1 = kr1[0], kc2 = kr2[0], kc3 = kr3[0];
        #pragma unroll 1
        for (int idx = 0; idx < 64; ++idx) {
            const int nidx = (idx + 1) & 63;          // wrap: last prefetch unused
            const float* qb = &qs[0][side * SUB];

            float4 q0 = ((const float4*)(qb + 0 * Dd))[idx];
            float4 q1 = ((const float4*)(qb + 1 * Dd))[idx];
            float4 q2 = ((const float4*)(qb + 2 * Dd))[idx];
            float4 q3 = ((const float4*)(qb + 3 * Dd))[idx];

            float4 kn0 = kr0[nidx], kn1 = kr1[nidx], kn2 = kr2[nidx], kn3 = kr3[nidx];

            #define FMA16(r, qv)                                     \
                acc[r][0] = fmaf(qv.x, kc0.x, acc[r][0]);            \
                acc[r][1] = fmaf(qv.x, kc1.x, acc[r][1]);            \
                acc[r][2] = fmaf(qv.x, kc2.x, acc[r][2]);            \
                acc[r][3] = fmaf(qv.x, kc3.x, acc[r][3]);            \
                acc[r][0] = fmaf(qv.y, kc0.y, acc[r][0]);            \
                acc[r][1] = fmaf(qv.y, kc1.y, acc[r][1]);            \
                acc[r][2] = fmaf(qv.y, kc2.y, acc[r][2]);            \
                acc[r][3] = fmaf(qv.y, kc3.y, acc[r][3]);            \
                acc[r][0] = fmaf(qv.z, kc0.z, acc[r][0]);            \
                acc[r][1] = fmaf(qv.z, kc1.z, acc[r][1]);            \
                acc[r][2] = fmaf(qv.z, kc2.z, acc[r][2]);            \
                acc[r][3] = fmaf(qv.z, kc3.z, acc[r][3]);            \
                acc[r][0] = fmaf(qv.w, kc0.w, acc[r][0]);            \
                acc[r][1] = fmaf(qv.w, kc1.w, acc[r][1]);            \
                acc[r][2] = fmaf(qv.w, kc2.w, acc[r][2]);            \
                acc[r][3] = fmaf(qv.w, kc3.w, acc[r][3]);

            FMA16(0, q0)
            FMA16(1, q1)
            float4 q4 = ((const float4*)(qb + 4 * Dd))[idx];
            float4 q5 = ((const float4*)(qb + 5 * Dd))[idx];
            float4 q6 = ((const float4*)(qb + 6 * Dd))[idx];
            float4 q7 = ((const float4*)(qb + 7 * Dd))[idx];
            FMA16(2, q2)
            FMA16(3, q3)
            FMA16(4, q4)
            FMA16(5, q5)
            FMA16(6, q6)
            FMA16(7, q7)
            #undef FMA16

            kc0 = kn0; kc1 = kn1; kc2 = kn2; kc3 = kn3;
        }

        // ---- phase 2: two batches of 4 rows; one row per wave ----
        #pragma unroll 1
        for (int batch = 0; batch < 2; ++batch) {
            // swizzled store: element k = g*256+t -> column k ^ (((k>>4)&7)<<2)
            #pragma unroll
            for (int rr = 0; rr < 4; ++rr)
                #pragma unroll
                for (int g = 0; g < 4; ++g)
                    sc[rr][g * 256 + (t ^ X)] = acc[batch * 4 + rr][g];
            __syncthreads();

            const int r = batch * 4 + wave;       // actual row this wave selects
            float v[16];
            const float4* sp = (const float4*)sc[wave];
            #pragma unroll
            for (int c = 0; c < 4; ++c) {
                const int gidx = (4 * lane + c) ^ (lane & 7);   // swizzled granule
                float4 x = sp[gidx];
                v[4*c+0] = x.x; v[4*c+1] = x.y; v[4*c+2] = x.z; v[4*c+3] = x.w;
            }
            for (int it = 0; it < TK; ++it) {
                float lv = v[0]; int li = 0;
                #pragma unroll
                for (int i = 1; i < 16; ++i)
                    if (v[i] > lv) { lv = v[i]; li = i; }   // strict > : lowest i on ties
                float M = wave_fmax_bcast(lv);
                const int w = (int)__builtin_ctzll(__ballot(lv == M)); // lowest lane = lowest pos
                if (lane == w) { topv[side][r][it] = M; topi[side][r][it] = (lane << 4) | li; }
                const bool kk = (lane == w);
                #pragma unroll
                for (int i = 0; i < 16; ++i)                 // static-index elimination
                    v[i] = (kk && i == li) ? -INFINITY : v[i];
            }
            __syncthreads();
        }
    }

    // ---- phase 3: 32x32 product sums, top-32, softmax; lane owns p in [16l,16l+16) ----
    {
        const int ra = wave, rb = wave + 4;
        float va[16], vb[16];
        // p = 16*lane + i ; a = p>>5 = lane>>1 ; b = p&31 = 16*(lane&1)+i
        const float tla = topv[0][ra][lane >> 1];
        const float tlb = topv[0][rb][lane >> 1];
        const float4* t1a = (const float4*)topv[1][ra];
        const float4* t1b = (const float4*)topv[1][rb];
        #pragma unroll
        for (int c = 0; c < 4; ++c) {
            float4 xa = t1a[4 * (lane & 1) + c];
            float4 xb = t1b[4 * (lane & 1) + c];
            va[4*c+0] = __fadd_rn(tla, xa.x); va[4*c+1] = __fadd_rn(tla, xa.y);
            va[4*c+2] = __fadd_rn(tla, xa.z); va[4*c+3] = __fadd_rn(tla, xa.w);
            vb[4*c+0] = __fadd_rn(tlb, xb.x); vb[4*c+1] = __fadd_rn(tlb, xb.y);
            vb[4*c+2] = __fadd_rn(tlb, xb.z); vb[4*c+3] = __fadd_rn(tlb, xb.w);
        }
        float m0a = 0.0f, wva = 0.0f; int wpa = 0;
        float m0b = 0.0f, wvb = 0.0f; int wpb = 0;
        for (int it = 0; it < TK; ++it) {
            float la = va[0]; int ia = 0;
            float lb = vb[0]; int ib = 0;
            #pragma unroll
            for (int i = 1; i < 16; ++i) {
                if (va[i] > la) { la = va[i]; ia = i; }
                if (vb[i] > lb) { lb = vb[i]; ib = i; }
            }
            float Ma = wave_fmax_bcast(la);
            float Mb = wave_fmax_bcast(lb);
            const int wa = (int)__builtin_ctzll(__ballot(la == Ma));
            const int wb = (int)__builtin_ctzll(__ballot(lb == Mb));
            const int pa = (wa << 4) | __builtin_amdgcn_readlane(ia, wa);  // uniform
            const int pb = (wb << 4) | __builtin_amdgcn_readlane(ib, wb);
            if (it == 0) { m0a = Ma; m0b = Mb; }          // rank 0 = max
            if (lane == it) { wva = Ma; wpa = pa; wvb = Mb; wpb = pb; }
            const bool ka = (lane == wa), kb = (lane == wb);
            #pragma unroll
            for (int i = 0; i < 16; ++i) {
                va[i] = (ka && i == ia) ? -INFINITY : va[i];
                vb[i] = (kb && i == ib) ? -INFINITY : vb[i];
            }
        }
        float ea = (lane < TK) ? expf(wva - m0a) : 0.0f;
        float eb = (lane < TK) ? expf(wvb - m0b) : 0.0f;
        float sa = ea, sb = eb;
        #pragma unroll
        for (int m = 1; m < 64; m <<= 1) {
            sa += __shfl_xor(sa, m, 64);
            sb += __shfl_xor(sb, m, 64);
        }
        if (lane < TK) {
            {
                const int bc = bc0 + ra;
                const size_t base = ((size_t)bc * Hh + h) * TK;
                const int a = wpa >> 5;
                // reference quirk: product_indices[a*32+b] = l[a]*N + r[a]
                const int fl = topi[0][ra][a] * Nk + topi[1][ra][a];
                out[base + lane] = ea / sa;
                out[(size_t)W_ELEMS + base + lane] = (float)fl;
            }
            {
                const int bc = bc0 + rb;
                const size_t base = ((size_t)bc * Hh + h) * TK;
                const int a = wpb >> 5;
                const int fl = topi[0][rb][a] * Nk + topi[1][rb][a];
                out[base + lane] = eb / sb;
                out[(size_t)W_ELEMS + base + lane] = (float)fl;
            }
        }
    }
}

extern "C" void kernel_launch(void* const* d_in, const int* in_sizes, int n_in,
                              void* d_out, int out_size, void* d_ws, size_t ws_size,
                              hipStream_t stream)
{
    const float* query = (const float*)d_in[0];
    const float* keyl  = (const float*)d_in[1];
    const float* keyr  = (const float*)d_in[2];
    float* out = (float*)d_out;
    pk_kernel<<<dim3(8192), dim3(NT), 0, stream>>>(query, keyl, keyr, out);
}

// Round 7
// 2982.567 us; speedup vs baseline: 1.4138x; 1.4138x over previous
//
#include <hip/hip_runtime.h>
#include <math.h>

#define Hh  8
#define Dd  512
#define SUB 256          // D/2
#define Nk  1024         // num_subkeys
#define TK  32           // top_k
#define Rr  8            // rows (b,c) per block
#define NT  256
#define W_ELEMS (65536 * 32)

// Phase-1 arithmetic: single accumulator per (row,key), strictly sequential
// FUSED-FMA chain over the contraction dim in natural order (d = 0..255) —
// bit-identical to all previous rounds.
//
// R7: SPILL FIX. Evidence across R1-R6: __launch_bounds__ 2nd arg N makes the
// AMDGPU backend target ~2N waves/EU -> VGPR cap 512/(2N):
//   (256,2)->cap 128 (R1/R2: VGPR 52/68, WRITE 16 MB clean)
//   (256,3)->cap ~85 (R4/R5: VGPR 84, 136-401 MB scratch)
//   (256,4)->cap  64 (R3/R6: VGPR 64, 500-830 MB scratch)
// The phase-1 body needs ~90-110 VGPRs. So: bounds (256,2) + LDS 36.8 KB
// (batched sc[4][Nk]) -> 4 blocks/CU by LDS, no spill.
//   - q broadcast from LDS once per (js,c,row) feeding all 4 key groups
//   - selection: DPP value-max + ballot/ctz tie-break, static elimination;
//     lane l owns keys [16l,16l+16); sc XOR-swizzled (conflict-free)

__device__ __forceinline__ float wave_fmax_bcast(float x) {
    // classic gfx9 DPP max-reduce; result broadcast via readlane(63).
    int v;
    v = __builtin_amdgcn_update_dpp(0xff800000, __float_as_int(x), 0x111, 0xf, 0xf, false);
    x = fmaxf(x, __int_as_float(v));   // row_shr:1
    v = __builtin_amdgcn_update_dpp(0xff800000, __float_as_int(x), 0x112, 0xf, 0xf, false);
    x = fmaxf(x, __int_as_float(v));   // row_shr:2
    v = __builtin_amdgcn_update_dpp(0xff800000, __float_as_int(x), 0x114, 0xf, 0xf, false);
    x = fmaxf(x, __int_as_float(v));   // row_shr:4
    v = __builtin_amdgcn_update_dpp(0xff800000, __float_as_int(x), 0x118, 0xf, 0xf, false);
    x = fmaxf(x, __int_as_float(v));   // row_shr:8  -> lane15 of each row16 = row max
    v = __builtin_amdgcn_update_dpp(0xff800000, __float_as_int(x), 0x142, 0xa, 0xf, false);
    x = fmaxf(x, __int_as_float(v));   // row_bcast:15
    v = __builtin_amdgcn_update_dpp(0xff800000, __float_as_int(x), 0x143, 0xc, 0xf, false);
    x = fmaxf(x, __int_as_float(v));   // row_bcast:31 -> lane 63 = wave max
    return __int_as_float(__builtin_amdgcn_readlane(__float_as_int(x), 63));
}

__global__ __launch_bounds__(NT, 2)
void pk_kernel(const float* __restrict__ query,
               const float* __restrict__ keyl,
               const float* __restrict__ keyr,
               float* __restrict__ out)
{
    __shared__ __attribute__((aligned(16))) float qs[Rr][Dd];      // 16 KB
    __shared__ __attribute__((aligned(16))) float sc[4][Nk];       // 16 KB (swizzled)
    __shared__ __attribute__((aligned(16))) float topv[2][Rr][TK]; // 2 KB
    __shared__ __attribute__((aligned(16))) int   topi[2][Rr][TK]; // 2 KB

    const int bid  = blockIdx.x;
    const int h    = bid >> 10;           // h-major for L2 key locality
    const int tile = bid & 1023;
    const int bc0  = tile * Rr;
    const int t    = threadIdx.x;
    const int lane = t & 63;
    const int wave = t >> 6;

    // ---- stage query tile to LDS, fully coalesced ----
    #pragma unroll
    for (int rw = 0; rw < 2; ++rw) {
        const int r = wave * 2 + rw;
        const float4* src = (const float4*)(query + ((size_t)(bc0 + r) * Hh + h) * Dd);
        float4* dst = (float4*)qs[r];
        dst[lane]      = src[lane];
        dst[lane + 64] = src[lane + 64];
    }
    __syncthreads();

    const int X = ((t >> 4) & 7) << 2;    // store-swizzle for this thread

    for (int side = 0; side < 2; ++side) {
        const float* kbase = (side == 0 ? keyl : keyr) + (size_t)h * Nk * SUB;

        const float4* kr0 = (const float4*)(kbase + (size_t)(0 * 256 + t) * SUB);
        const float4* kr1 = (const float4*)(kbase + (size_t)(1 * 256 + t) * SUB);
        const float4* kr2 = (const float4*)(kbase + (size_t)(2 * 256 + t) * SUB);
        const float4* kr3 = (const float4*)(kbase + (size_t)(3 * 256 + t) * SUB);

        float acc[Rr][4];
        #pragma unroll
        for (int r = 0; r < Rr; ++r)
            #pragma unroll
            for (int g = 0; g < 4; ++g) acc[r][g] = 0.0f;

        // ---- phase 1: q broadcast from LDS once per (js,c,row), 4 keys/thread ----
        #pragma unroll 1
        for (int js = 0; js < 16; ++js) {
            #pragma unroll
            for (int c = 0; c < 4; ++c) {
                const int idx = 4 * js + c;
                float4 k0 = kr0[idx], k1 = kr1[idx], k2 = kr2[idx], k3 = kr3[idx];
                #pragma unroll
                for (int r = 0; r < Rr; ++r) {
                    float4 qv = ((const float4*)&qs[r][side * SUB])[idx];
                    acc[r][0] = fmaf(qv.x, k0.x, acc[r][0]);
                    acc[r][1] = fmaf(qv.x, k1.x, acc[r][1]);
                    acc[r][2] = fmaf(qv.x, k2.x, acc[r][2]);
                    acc[r][3] = fmaf(qv.x, k3.x, acc[r][3]);
                    acc[r][0] = fmaf(qv.y, k0.y, acc[r][0]);
                    acc[r][1] = fmaf(qv.y, k1.y, acc[r][1]);
                    acc[r][2] = fmaf(qv.y, k2.y, acc[r][2]);
                    acc[r][3] = fmaf(qv.y, k3.y, acc[r][3]);
                    acc[r][0] = fmaf(qv.z, k0.z, acc[r][0]);
                    acc[r][1] = fmaf(qv.z, k1.z, acc[r][1]);
                    acc[r][2] = fmaf(qv.z, k2.z, acc[r][2]);
                    acc[r][3] = fmaf(qv.z, k3.z, acc[r][3]);
                    acc[r][0] = fmaf(qv.w, k0.w, acc[r][0]);
                    acc[r][1] = fmaf(qv.w, k1.w, acc[r][1]);
                    acc[r][2] = fmaf(qv.w, k2.w, acc[r][2]);
                    acc[r][3] = fmaf(qv.w, k3.w, acc[r][3]);
                }
            }
        }

        // ---- phase 2: two batches of 4 rows; one row per wave ----
        #pragma unroll 1
        for (int batch = 0; batch < 2; ++batch) {
            // swizzled store: element k = g*256+t -> column k ^ (((k>>4)&7)<<2)
            #pragma unroll
            for (int rr = 0; rr < 4; ++rr)
                #pragma unroll
                for (int g = 0; g < 4; ++g)
                    sc[rr][g * 256 + (t ^ X)] = acc[batch * 4 + rr][g];
            __syncthreads();

            const int r = batch * 4 + wave;       // actual row this wave selects
            float v[16];
            const float4* sp = (const float4*)sc[wave];
            #pragma unroll
            for (int c = 0; c < 4; ++c) {
                const int gidx = (4 * lane + c) ^ (lane & 7);   // swizzled granule
                float4 x = sp[gidx];
                v[4*c+0] = x.x; v[4*c+1] = x.y; v[4*c+2] = x.z; v[4*c+3] = x.w;
            }
            for (int it = 0; it < TK; ++it) {
                float lv = v[0]; int li = 0;
                #pragma unroll
                for (int i = 1; i < 16; ++i)
                    if (v[i] > lv) { lv = v[i]; li = i; }   // strict > : lowest i on ties
                float M = wave_fmax_bcast(lv);
                const int w = (int)__builtin_ctzll(__ballot(lv == M)); // lowest lane = lowest pos
                if (lane == w) { topv[side][r][it] = M; topi[side][r][it] = (lane << 4) | li; }
                const bool kk = (lane == w);
                #pragma unroll
                for (int i = 0; i < 16; ++i)                 // static-index elimination
                    v[i] = (kk && i == li) ? -INFINITY : v[i];
            }
            __syncthreads();
        }
    }

    // ---- phase 3: 32x32 product sums, top-32, softmax; lane owns p in [16l,16l+16) ----
    {
        const int ra = wave, rb = wave + 4;
        float va[16], vb[16];
        // p = 16*lane + i ; a = p>>5 = lane>>1 ; b = p&31 = 16*(lane&1)+i
        const float tla = topv[0][ra][lane >> 1];
        const float tlb = topv[0][rb][lane >> 1];
        const float4* t1a = (const float4*)topv[1][ra];
        const float4* t1b = (const float4*)topv[1][rb];
        #pragma unroll
        for (int c = 0; c < 4; ++c) {
            float4 xa = t1a[4 * (lane & 1) + c];
            float4 xb = t1b[4 * (lane & 1) + c];
            va[4*c+0] = __fadd_rn(tla, xa.x); va[4*c+1] = __fadd_rn(tla, xa.y);
            va[4*c+2] = __fadd_rn(tla, xa.z); va[4*c+3] = __fadd_rn(tla, xa.w);
            vb[4*c+0] = __fadd_rn(tlb, xb.x); vb[4*c+1] = __fadd_rn(tlb, xb.y);
            vb[4*c+2] = __fadd_rn(tlb, xb.z); vb[4*c+3] = __fadd_rn(tlb, xb.w);
        }
        float m0a = 0.0f, wva = 0.0f; int wpa = 0;
        float m0b = 0.0f, wvb = 0.0f; int wpb = 0;
        for (int it = 0; it < TK; ++it) {
            float la = va[0]; int ia = 0;
            float lb = vb[0]; int ib = 0;
            #pragma unroll
            for (int i = 1; i < 16; ++i) {
                if (va[i] > la) { la = va[i]; ia = i; }
                if (vb[i] > lb) { lb = vb[i]; ib = i; }
            }
            float Ma = wave_fmax_bcast(la);
            float Mb = wave_fmax_bcast(lb);
            const int wa = (int)__builtin_ctzll(__ballot(la == Ma));
            const int wb = (int)__builtin_ctzll(__ballot(lb == Mb));
            const int pa = (wa << 4) | __builtin_amdgcn_readlane(ia, wa);  // uniform
            const int pb = (wb << 4) | __builtin_amdgcn_readlane(ib, wb);
            if (it == 0) { m0a = Ma; m0b = Mb; }          // rank 0 = max
            if (lane == it) { wva = Ma; wpa = pa; wvb = Mb; wpb = pb; }
            const bool ka = (lane == wa), kb = (lane == wb);
            #pragma unroll
            for (int i = 0; i < 16; ++i) {
                va[i] = (ka && i == ia) ? -INFINITY : va[i];
                vb[i] = (kb && i == ib) ? -INFINITY : vb[i];
            }
        }
        float ea = (lane < TK) ? expf(wva - m0a) : 0.0f;
        float eb = (lane < TK) ? expf(wvb - m0b) : 0.0f;
        float sa = ea, sb = eb;
        #pragma unroll
        for (int m = 1; m < 64; m <<= 1) {
            sa += __shfl_xor(sa, m, 64);
            sb += __shfl_xor(sb, m, 64);
        }
        if (lane < TK) {
            {
                const int bc = bc0 + ra;
                const size_t base = ((size_t)bc * Hh + h) * TK;
                const int a = wpa >> 5;
                // reference quirk: product_indices[a*32+b] = l[a]*N + r[a]
                const int fl = topi[0][ra][a] * Nk + topi[1][ra][a];
                out[base + lane] = ea / sa;
                out[(size_t)W_ELEMS + base + lane] = (float)fl;
            }
            {
                const int bc = bc0 + rb;
                const size_t base = ((size_t)bc * Hh + h) * TK;
                const int a = wpb >> 5;
                const int fl = topi[0][rb][a] * Nk + topi[1][rb][a];
                out[base + lane] = eb / sb;
                out[(size_t)W_ELEMS + base + lane] = (float)fl;
            }
        }
    }
}

extern "C" void kernel_launch(void* const* d_in, const int* in_sizes, int n_in,
                              void* d_out, int out_size, void* d_ws, size_t ws_size,
                              hipStream_t stream)
{
    const float* query = (const float*)d_in[0];
    const float* keyl  = (const float*)d_in[1];
    const float* keyr  = (const float*)d_in[2];
    float* out = (float*)d_out;
    pk_kernel<<<dim3(8192), dim3(NT), 0, stream>>>(query, keyl, keyr, out);
}

// Round 8
// 2496.893 us; speedup vs baseline: 1.6888x; 1.1945x over previous
//
#include <hip/hip_runtime.h>
#include <math.h>

#define Hh  8
#define Dd  512
#define SUB 256          // D/2
#define Nk  1024         // num_subkeys
#define TK  32           // top_k
#define Rr  8            // rows (b,c) per block
#define NT  256
#define W_ELEMS (65536 * 32)

// Phase-1 arithmetic: single accumulator per (row,key), strictly sequential
// FUSED-FMA chain over the contraction dim in natural order (d = 0..255) —
// bit-identical to all previous rounds.
//
// R8: SCRATCH FIX (rule #20). R6/R7 wrote acc[batch*4+rr] inside a
// NON-unrolled batch loop -> runtime index into a register array -> LLVM
// demoted acc to scratch (600 MB WRITE / 392 MB FETCH = exactly a
// 32-float x 256-thr x 8192-blk x 2-side scratch copy + readback).
// Fix: batch loop FULLY UNROLLED -> every acc access statically indexed.
// Everything else unchanged from R7:
//   - q broadcast from LDS once per (js,c,row) feeding all 4 key groups
//   - selection: DPP value-max + ballot/ctz tie-break, static elimination;
//     lane l owns keys [16l,16l+16); sc XOR-swizzled (conflict-free)
//   - sc[4][Nk] batched (LDS 36.8 KB -> 4 blocks/CU), bounds (256,2)

__device__ __forceinline__ float wave_fmax_bcast(float x) {
    // classic gfx9 DPP max-reduce; result broadcast via readlane(63).
    int v;
    v = __builtin_amdgcn_update_dpp(0xff800000, __float_as_int(x), 0x111, 0xf, 0xf, false);
    x = fmaxf(x, __int_as_float(v));   // row_shr:1
    v = __builtin_amdgcn_update_dpp(0xff800000, __float_as_int(x), 0x112, 0xf, 0xf, false);
    x = fmaxf(x, __int_as_float(v));   // row_shr:2
    v = __builtin_amdgcn_update_dpp(0xff800000, __float_as_int(x), 0x114, 0xf, 0xf, false);
    x = fmaxf(x, __int_as_float(v));   // row_shr:4
    v = __builtin_amdgcn_update_dpp(0xff800000, __float_as_int(x), 0x118, 0xf, 0xf, false);
    x = fmaxf(x, __int_as_float(v));   // row_shr:8  -> lane15 of each row16 = row max
    v = __builtin_amdgcn_update_dpp(0xff800000, __float_as_int(x), 0x142, 0xa, 0xf, false);
    x = fmaxf(x, __int_as_float(v));   // row_bcast:15
    v = __builtin_amdgcn_update_dpp(0xff800000, __float_as_int(x), 0x143, 0xc, 0xf, false);
    x = fmaxf(x, __int_as_float(v));   // row_bcast:31 -> lane 63 = wave max
    return __int_as_float(__builtin_amdgcn_readlane(__float_as_int(x), 63));
}

__global__ __launch_bounds__(NT, 2)
void pk_kernel(const float* __restrict__ query,
               const float* __restrict__ keyl,
               const float* __restrict__ keyr,
               float* __restrict__ out)
{
    __shared__ __attribute__((aligned(16))) float qs[Rr][Dd];      // 16 KB
    __shared__ __attribute__((aligned(16))) float sc[4][Nk];       // 16 KB (swizzled)
    __shared__ __attribute__((aligned(16))) float topv[2][Rr][TK]; // 2 KB
    __shared__ __attribute__((aligned(16))) int   topi[2][Rr][TK]; // 2 KB

    const int bid  = blockIdx.x;
    const int h    = bid >> 10;           // h-major for L2 key locality
    const int tile = bid & 1023;
    const int bc0  = tile * Rr;
    const int t    = threadIdx.x;
    const int lane = t & 63;
    const int wave = t >> 6;

    // ---- stage query tile to LDS, fully coalesced ----
    #pragma unroll
    for (int rw = 0; rw < 2; ++rw) {
        const int r = wave * 2 + rw;
        const float4* src = (const float4*)(query + ((size_t)(bc0 + r) * Hh + h) * Dd);
        float4* dst = (float4*)qs[r];
        dst[lane]      = src[lane];
        dst[lane + 64] = src[lane + 64];
    }
    __syncthreads();

    const int X = ((t >> 4) & 7) << 2;    // store-swizzle for this thread

    for (int side = 0; side < 2; ++side) {
        const float* kbase = (side == 0 ? keyl : keyr) + (size_t)h * Nk * SUB;

        const float4* kr0 = (const float4*)(kbase + (size_t)(0 * 256 + t) * SUB);
        const float4* kr1 = (const float4*)(kbase + (size_t)(1 * 256 + t) * SUB);
        const float4* kr2 = (const float4*)(kbase + (size_t)(2 * 256 + t) * SUB);
        const float4* kr3 = (const float4*)(kbase + (size_t)(3 * 256 + t) * SUB);

        float acc[Rr][4];
        #pragma unroll
        for (int r = 0; r < Rr; ++r)
            #pragma unroll
            for (int g = 0; g < 4; ++g) acc[r][g] = 0.0f;

        // ---- phase 1: q broadcast from LDS once per (js,c,row), 4 keys/thread ----
        #pragma unroll 1
        for (int js = 0; js < 16; ++js) {
            #pragma unroll
            for (int c = 0; c < 4; ++c) {
                const int idx = 4 * js + c;
                float4 k0 = kr0[idx], k1 = kr1[idx], k2 = kr2[idx], k3 = kr3[idx];
                #pragma unroll
                for (int r = 0; r < Rr; ++r) {
                    float4 qv = ((const float4*)&qs[r][side * SUB])[idx];
                    acc[r][0] = fmaf(qv.x, k0.x, acc[r][0]);
                    acc[r][1] = fmaf(qv.x, k1.x, acc[r][1]);
                    acc[r][2] = fmaf(qv.x, k2.x, acc[r][2]);
                    acc[r][3] = fmaf(qv.x, k3.x, acc[r][3]);
                    acc[r][0] = fmaf(qv.y, k0.y, acc[r][0]);
                    acc[r][1] = fmaf(qv.y, k1.y, acc[r][1]);
                    acc[r][2] = fmaf(qv.y, k2.y, acc[r][2]);
                    acc[r][3] = fmaf(qv.y, k3.y, acc[r][3]);
                    acc[r][0] = fmaf(qv.z, k0.z, acc[r][0]);
                    acc[r][1] = fmaf(qv.z, k1.z, acc[r][1]);
                    acc[r][2] = fmaf(qv.z, k2.z, acc[r][2]);
                    acc[r][3] = fmaf(qv.z, k3.z, acc[r][3]);
                    acc[r][0] = fmaf(qv.w, k0.w, acc[r][0]);
                    acc[r][1] = fmaf(qv.w, k1.w, acc[r][1]);
                    acc[r][2] = fmaf(qv.w, k2.w, acc[r][2]);
                    acc[r][3] = fmaf(qv.w, k3.w, acc[r][3]);
                }
            }
        }

        // ---- phase 2: two batches of 4 rows; one row per wave ----
        // batch loop FULLY UNROLLED: acc[] indices must be compile-time
        // constants or the allocator demotes acc to scratch (rule #20).
        #pragma unroll
        for (int batch = 0; batch < 2; ++batch) {
            // swizzled store: element k = g*256+t -> column k ^ (((k>>4)&7)<<2)
            #pragma unroll
            for (int rr = 0; rr < 4; ++rr)
                #pragma unroll
                for (int g = 0; g < 4; ++g)
                    sc[rr][g * 256 + (t ^ X)] = acc[batch * 4 + rr][g];
            __syncthreads();

            const int r = batch * 4 + wave;       // actual row this wave selects
            float v[16];
            const float4* sp = (const float4*)sc[wave];
            #pragma unroll
            for (int c = 0; c < 4; ++c) {
                const int gidx = (4 * lane + c) ^ (lane & 7);   // swizzled granule
                float4 x = sp[gidx];
                v[4*c+0] = x.x; v[4*c+1] = x.y; v[4*c+2] = x.z; v[4*c+3] = x.w;
            }
            for (int it = 0; it < TK; ++it) {
                float lv = v[0]; int li = 0;
                #pragma unroll
                for (int i = 1; i < 16; ++i)
                    if (v[i] > lv) { lv = v[i]; li = i; }   // strict > : lowest i on ties
                float M = wave_fmax_bcast(lv);
                const int w = (int)__builtin_ctzll(__ballot(lv == M)); // lowest lane = lowest pos
                if (lane == w) { topv[side][r][it] = M; topi[side][r][it] = (lane << 4) | li; }
                const bool kk = (lane == w);
                #pragma unroll
                for (int i = 0; i < 16; ++i)                 // static-index elimination
                    v[i] = (kk && i == li) ? -INFINITY : v[i];
            }
            __syncthreads();
        }
    }

    // ---- phase 3: 32x32 product sums, top-32, softmax; lane owns p in [16l,16l+16) ----
    {
        const int ra = wave, rb = wave + 4;
        float va[16], vb[16];
        // p = 16*lane + i ; a = p>>5 = lane>>1 ; b = p&31 = 16*(lane&1)+i
        const float tla = topv[0][ra][lane >> 1];
        const float tlb = topv[0][rb][lane >> 1];
        const float4* t1a = (const float4*)topv[1][ra];
        const float4* t1b = (const float4*)topv[1][rb];
        #pragma unroll
        for (int c = 0; c < 4; ++c) {
            float4 xa = t1a[4 * (lane & 1) + c];
            float4 xb = t1b[4 * (lane & 1) + c];
            va[4*c+0] = __fadd_rn(tla, xa.x); va[4*c+1] = __fadd_rn(tla, xa.y);
            va[4*c+2] = __fadd_rn(tla, xa.z); va[4*c+3] = __fadd_rn(tla, xa.w);
            vb[4*c+0] = __fadd_rn(tlb, xb.x); vb[4*c+1] = __fadd_rn(tlb, xb.y);
            vb[4*c+2] = __fadd_rn(tlb, xb.z); vb[4*c+3] = __fadd_rn(tlb, xb.w);
        }
        float m0a = 0.0f, wva = 0.0f; int wpa = 0;
        float m0b = 0.0f, wvb = 0.0f; int wpb = 0;
        for (int it = 0; it < TK; ++it) {
            float la = va[0]; int ia = 0;
            float lb = vb[0]; int ib = 0;
            #pragma unroll
            for (int i = 1; i < 16; ++i) {
                if (va[i] > la) { la = va[i]; ia = i; }
                if (vb[i] > lb) { lb = vb[i]; ib = i; }
            }
            float Ma = wave_fmax_bcast(la);
            float Mb = wave_fmax_bcast(lb);
            const int wa = (int)__builtin_ctzll(__ballot(la == Ma));
            const int wb = (int)__builtin_ctzll(__ballot(lb == Mb));
            const int pa = (wa << 4) | __builtin_amdgcn_readlane(ia, wa);  // uniform
            const int pb = (wb << 4) | __builtin_amdgcn_readlane(ib, wb);
            if (it == 0) { m0a = Ma; m0b = Mb; }          // rank 0 = max
            if (lane == it) { wva = Ma; wpa = pa; wvb = Mb; wpb = pb; }
            const bool ka = (lane == wa), kb = (lane == wb);
            #pragma unroll
            for (int i = 0; i < 16; ++i) {
                va[i] = (ka && i == ia) ? -INFINITY : va[i];
                vb[i] = (kb && i == ib) ? -INFINITY : vb[i];
            }
        }
        float ea = (lane < TK) ? expf(wva - m0a) : 0.0f;
        float eb = (lane < TK) ? expf(wvb - m0b) : 0.0f;
        float sa = ea, sb = eb;
        #pragma unroll
        for (int m = 1; m < 64; m <<= 1) {
            sa += __shfl_xor(sa, m, 64);
            sb += __shfl_xor(sb, m, 64);
        }
        if (lane < TK) {
            {
                const int bc = bc0 + ra;
                const size_t base = ((size_t)bc * Hh + h) * TK;
                const int a = wpa >> 5;
                // reference quirk: product_indices[a*32+b] = l[a]*N + r[a]
                const int fl = topi[0][ra][a] * Nk + topi[1][ra][a];
                out[base + lane] = ea / sa;
                out[(size_t)W_ELEMS + base + lane] = (float)fl;
            }
            {
                const int bc = bc0 + rb;
                const size_t base = ((size_t)bc * Hh + h) * TK;
                const int a = wpb >> 5;
                const int fl = topi[0][rb][a] * Nk + topi[1][rb][a];
                out[base + lane] = eb / sb;
                out[(size_t)W_ELEMS + base + lane] = (float)fl;
            }
        }
    }
}

extern "C" void kernel_launch(void* const* d_in, const int* in_sizes, int n_in,
                              void* d_out, int out_size, void* d_ws, size_t ws_size,
                              hipStream_t stream)
{
    const float* query = (const float*)d_in[0];
    const float* keyl  = (const float*)d_in[1];
    const float* keyr  = (const float*)d_in[2];
    float* out = (float*)d_out;
    pk_kernel<<<dim3(8192), dim3(NT), 0, stream>>>(query, keyl, keyr, out);
}